// Round 6
// baseline (346.049 us; speedup 1.0000x reference)
//
#include <hip/hip_runtime.h>

// NonLocalAttention n=4, c=64, hw=6400.
// conv (MFMA bf16 hi/lo-compensated) -> bf16 Q(log2e-scaled)[n,p,c],
// K[n,p,c], V[n,c,p].
// LDS-FREE split-K flash attention: grid 1000 (XCD-swizzled so each XCD's L2
// holds one batch's K/V), 256q/block, 64q/wave, no barriers in the main loop.
// A/B fragments read straight from global (L1/L2-resident tiles); S^T=mfma(K,Q)
// with C-init=-SHIFT; S->PV fused per 32-key half (P live = 8 regs); PV
// A-fragments via lane^32 quad exchange. bf16 partial O -> combine kernel.

typedef __attribute__((ext_vector_type(8))) unsigned short us8;
typedef __attribute__((ext_vector_type(4))) unsigned short us4;
typedef __attribute__((ext_vector_type(8))) __bf16 bf16x8;
typedef __attribute__((ext_vector_type(16))) float f32x16;

#define HW 6400
#define L2E 1.44269504088896340736f
#define SHIFT 32.0f
#define KS 10
#define ITERS 10  // (HW/64)/KS

union V8 { us8 s; us4 h[2]; bf16x8 b; unsigned u4[4]; };

__device__ __forceinline__ unsigned short f32_to_bf16(float f) {
  unsigned u = __float_as_uint(f);
  u += 0x7fffu + ((u >> 16) & 1u);  // RNE; finite inputs
  return (unsigned short)(u >> 16);
}
__device__ __forceinline__ float bf16_bits_to_f32(unsigned short u) {
  return __uint_as_float(((unsigned)u) << 16);
}
__device__ __forceinline__ unsigned pack_bf16x2(float a, float b) {
#if __has_builtin(__builtin_amdgcn_cvt_pk_bf16_f32)
  auto v = __builtin_amdgcn_cvt_pk_bf16_f32(a, b);
  unsigned u;
  __builtin_memcpy(&u, &v, 4);
  return u;
#else
  unsigned ua = __float_as_uint(a); ua += 0x7fffu + ((ua >> 16) & 1u);
  unsigned ub = __float_as_uint(b); ub += 0x7fffu + ((ub >> 16) & 1u);
  return (ua >> 16) | (ub & 0xffff0000u);
#endif
}

// split 8 fp32 -> bf16 hi fragment + bf16 lo (residual) fragment
__device__ __forceinline__ void split_hilo(const float* f, V8& hi, V8& lo) {
#pragma unroll
  for (int j = 0; j < 8; ++j) {
    const unsigned short h = f32_to_bf16(f[j]);
    const float r = f[j] - bf16_bits_to_f32(h);
    hi.s[j] = h;
    lo.s[j] = f32_to_bf16(r);
  }
}

// ---------------------------------------------------------------------------
// Conv via MFMA: grid (50, 4) x 256 thr. Block = one n, 128 pixels, 3 convs.
// (Wh+Wl)(Xh+Xl) with 3 MFMAs per tile -> fp32-equivalent accuracy.
// ---------------------------------------------------------------------------
__global__ __launch_bounds__(256, 2) void conv_kernel(
    const float* __restrict__ x,
    const float* __restrict__ w1, const float* __restrict__ b1,
    const float* __restrict__ w2, const float* __restrict__ b2,
    const float* __restrict__ w3, const float* __restrict__ b3,
    unsigned short* __restrict__ Qg, unsigned short* __restrict__ Kg,
    unsigned short* __restrict__ Vg) {
  __shared__ __align__(16) float xs[64 * 132];           // X tile fp32
  __shared__ __align__(16) unsigned short tb[128 * 72];  // [p][c] transpose buf

  const int t = threadIdx.x;
  const int n = blockIdx.y;
  const int p0 = blockIdx.x * 128;
  const int wv = t >> 6;
  const int lane = t & 63;
  const int l31 = lane & 31;
  const int lh = lane >> 5;
  const int ob = (wv & 1) * 32;   // o-row base
  const int pw = (wv >> 1) * 64;  // pixel base within block

  {  // stage X tile [64 c][128 p] fp32
    const int c = t >> 2, qq = t & 3;
    const float* src = x + ((size_t)(n * 64 + c) * HW + p0 + qq * 32);
    float* dst = xs + c * 132 + qq * 32;
#pragma unroll
    for (int i = 0; i < 8; ++i)
      *(float4*)(dst + i * 4) = *(const float4*)(src + i * 4);
  }
  __syncthreads();

  const float* wms[3] = {w1, w2, w3};
  const float* bms[3] = {b1, b2, b3};

#pragma unroll 1
  for (int k = 0; k < 3; ++k) {
    const float* wm = wms[k];
    const float* bm = bms[k];

    V8 ah[4], al[4];
#pragma unroll
    for (int kst = 0; kst < 4; ++kst) {
      const float* wr = wm + (size_t)(ob + l31) * 64 + kst * 16 + lh * 8;
      float wf[8];
      *(float4*)(wf) = *(const float4*)wr;
      *(float4*)(wf + 4) = *(const float4*)(wr + 4);
      split_hilo(wf, ah[kst], al[kst]);
    }

    f32x16 acc[2];
#pragma unroll
    for (int pb = 0; pb < 2; ++pb)
#pragma unroll
      for (int r = 0; r < 16; ++r) acc[pb][r] = 0.f;

#pragma unroll
    for (int kst = 0; kst < 4; ++kst) {
#pragma unroll
      for (int pb = 0; pb < 2; ++pb) {
        float xf[8];
        const float* xp = xs + (kst * 16 + lh * 8) * 132 + pw + pb * 32 + l31;
#pragma unroll
        for (int j = 0; j < 8; ++j) xf[j] = xp[j * 132];
        V8 bh, bl;
        split_hilo(xf, bh, bl);
        acc[pb] = __builtin_amdgcn_mfma_f32_32x32x16_bf16(al[kst].b, bh.b, acc[pb], 0, 0, 0);
        acc[pb] = __builtin_amdgcn_mfma_f32_32x32x16_bf16(ah[kst].b, bl.b, acc[pb], 0, 0, 0);
        acc[pb] = __builtin_amdgcn_mfma_f32_32x32x16_bf16(ah[kst].b, bh.b, acc[pb], 0, 0, 0);
      }
    }

    if (k < 2) {  // Q or K: transpose to [p][c] via LDS, then coalesced store
#pragma unroll
      for (int pb = 0; pb < 2; ++pb) {
#pragma unroll
        for (int rq = 0; rq < 4; ++rq) {
          const int o = ob + 8 * rq + 4 * lh;
          const int pcol = pw + pb * 32 + l31;
          float v[4];
#pragma unroll
          for (int j = 0; j < 4; ++j) {
            float a = acc[pb][4 * rq + j] + bm[o + j];
            a = fmaxf(a, 0.f) + 0.2f * fminf(a, 0.f);
            if (k == 0) a *= L2E;
            v[j] = a;
          }
          unsigned* dst = (unsigned*)(tb + pcol * 72 + o);
          dst[0] = pack_bf16x2(v[0], v[1]);
          dst[1] = pack_bf16x2(v[2], v[3]);
        }
      }
      __syncthreads();
      {
        const int p = t >> 1, half = t & 1;
        const unsigned short* src = tb + p * 72 + half * 32;
        unsigned short* dst = (k == 0 ? Qg : Kg) +
                              (size_t)(n * HW + p0 + p) * 64 + half * 32;
#pragma unroll
        for (int i = 0; i < 4; ++i) *(us8*)(dst + i * 8) = *(const us8*)(src + i * 8);
      }
      __syncthreads();  // tb reused by next conv
    } else {  // V [n,c,p]: direct coalesced 2B stores
#pragma unroll
      for (int pb = 0; pb < 2; ++pb) {
#pragma unroll
        for (int r = 0; r < 16; ++r) {
          const int o = ob + 8 * (r >> 2) + 4 * lh + (r & 3);
          const int pcol = pw + pb * 32 + l31;
          float a = acc[pb][r] + bm[o];
          a = fmaxf(a, 0.f) + 0.2f * fminf(a, 0.f);
          Vg[(size_t)(n * 64 + o) * HW + p0 + pcol] = f32_to_bf16(a);
        }
      }
    }
  }
}

// ---------------------------------------------------------------------------
// LDS-free split-K flash attention: 1D grid 1000 blocks x 256 thr (4 waves).
// Block id XCD-swizzled: id%8 in {2nb, 2nb+1} -> each XCD streams ONE batch's
// K/V (1.6 MB, fits 4 MB XCD L2). Wave = 64 q; 64 keys/iter, 10 iters.
// No __syncthreads in the main loop; fragments loaded per-lane from global.
// ---------------------------------------------------------------------------
__global__ __launch_bounds__(256, 3) void attn_kernel(
    const unsigned short* __restrict__ Qg, const unsigned short* __restrict__ Kg,
    const unsigned short* __restrict__ Vg, unsigned short* __restrict__ Opart,
    float* __restrict__ Lpart) {
  __shared__ __align__(16) unsigned short Otb[64 * 132];  // epilogue only

  const int t = threadIdx.x;
  const int w = t >> 6;
  const int lane = t & 63;
  const int l31 = lane & 31;
  const int lh = lane >> 5;

  // id -> (nb, qi, ks): id = (j>>1)*8 + 2*nb + (j&1), j = qi + 25*ks
  const int id = blockIdx.x;
  const int nb = (id >> 1) & 3;
  const int j = ((id >> 3) << 1) | (id & 1);
  const int qi = j % 25;
  const int ks = j / 25;
  const int qb = qi * 256;
  const int key0 = ks * (HW / KS);

  // loop-invariant Q fragments (B operand: col m = l31)
  V8 aQ[2][4];
#pragma unroll
  for (int qh = 0; qh < 2; ++qh) {
    const unsigned short* qrow =
        Qg + (size_t)(nb * HW + qb + w * 64 + qh * 32 + l31) * 64 + lh * 8;
#pragma unroll
    for (int kst = 0; kst < 4; ++kst) aQ[qh][kst].s = *(const us8*)(qrow + kst * 16);
  }

  f32x16 accO[2][2];
#pragma unroll
  for (int qh = 0; qh < 2; ++qh)
#pragma unroll
    for (int ci = 0; ci < 2; ++ci)
#pragma unroll
      for (int r = 0; r < 16; ++r) accO[qh][ci][r] = 0.f;
  float lp[2] = {0.f, 0.f};

  // per-lane fragment bases (elements)
  const unsigned short* kfrag =
      Kg + (size_t)(nb * HW + key0 + l31) * 64 + lh * 8;  // + jt*4096 + ni*2048 + kst*16
  const unsigned short* vfrag =
      Vg + (size_t)nb * 64 * HW + (size_t)l31 * HW + key0 + lh * 8;  // + ci*32*HW + jt*64 + kst*16

#pragma unroll 1
  for (int jt = 0; jt < ITERS; ++jt) {
    const unsigned short* kit = kfrag + jt * 4096;
    const unsigned short* vit = vfrag + jt * 64;

#pragma unroll
    for (int ni = 0; ni < 2; ++ni) {
      // K fragments for this 32-key half (reused by both q-halves)
      V8 ak[4];
#pragma unroll
      for (int kst = 0; kst < 4; ++kst)
        ak[kst].s = *(const us8*)(kit + ni * 2048 + kst * 16);
      // V fragments for keys of this half: kst in {2ni, 2ni+1}
      V8 bv[2][2];  // [ci][kk]
#pragma unroll
      for (int ci = 0; ci < 2; ++ci)
#pragma unroll
        for (int kk = 0; kk < 2; ++kk)
          bv[ci][kk].s =
              *(const us8*)(vit + (size_t)ci * 32 * HW + (2 * ni + kk) * 16);

#pragma unroll
      for (int qh = 0; qh < 2; ++qh) {
        // S^T = K Q^T for 32 keys x 64 q (cols m=l31), C-init = -SHIFT
        f32x16 sacc;
#pragma unroll
        for (int r = 0; r < 16; ++r) sacc[r] = -SHIFT;
#pragma unroll
        for (int kst = 0; kst < 4; ++kst)
          sacc = __builtin_amdgcn_mfma_f32_32x32x16_bf16(ak[kst].b,
                                                         aQ[qh][kst].b, sacc, 0, 0, 0);
        // exp2 + pack; pkg[g] = keys ni*32+8g+4lh+{0..3}
        uint2 pkg[4];
#pragma unroll
        for (int g = 0; g < 4; ++g) {
          const float p0 = __builtin_amdgcn_exp2f(sacc[4 * g + 0]);
          const float p1 = __builtin_amdgcn_exp2f(sacc[4 * g + 1]);
          const float p2 = __builtin_amdgcn_exp2f(sacc[4 * g + 2]);
          const float p3 = __builtin_amdgcn_exp2f(sacc[4 * g + 3]);
          lp[qh] += (p0 + p1) + (p2 + p3);
          pkg[g].x = pack_bf16x2(p0, p1);
          pkg[g].y = pack_bf16x2(p2, p3);
        }
        // PV for these 32 keys: kst = 2ni+kk; lane^32 quad exchange
#pragma unroll
        for (int kk = 0; kk < 2; ++kk) {
          const int gb = 2 * kk;
          const uint2 qa = pkg[gb];
          const uint2 qb2 = pkg[gb + 1];
          uint2 send;
          send.x = lh ? qa.x : qb2.x;
          send.y = lh ? qa.y : qb2.y;
          uint2 recv;
          recv.x = __shfl_xor(send.x, 32);
          recv.y = __shfl_xor(send.y, 32);
          const uint2 keep = {lh ? qb2.x : qa.x, lh ? qb2.y : qa.y};
          V8 ap;
          ap.u4[0] = lh ? recv.x : keep.x;
          ap.u4[1] = lh ? recv.y : keep.y;
          ap.u4[2] = lh ? keep.x : recv.x;
          ap.u4[3] = lh ? keep.y : recv.y;
          accO[qh][0] = __builtin_amdgcn_mfma_f32_32x32x16_bf16(
              ap.b, bv[0][kk].b, accO[qh][0], 0, 0, 0);
          accO[qh][1] = __builtin_amdgcn_mfma_f32_32x32x16_bf16(
              ap.b, bv[1][kk].b, accO[qh][1], 0, 0, 0);
        }
      }
    }
  }

  // l reduce + store
#pragma unroll
  for (int qh = 0; qh < 2; ++qh) {
    const float lsum = lp[qh] + __shfl_xor(lp[qh], 32);
    if (lh == 0)
      Lpart[((size_t)ks * 4 + nb) * HW + qb + w * 64 + qh * 32 + l31] = lsum;
  }

  // epilogue: two 128-q passes through Otb[64][132] bf16 (66-dword row
  // stride -> 2-bank rotation, conflict-free); coalesced us8 stores.
#pragma unroll 1
  for (int pi = 0; pi < 2; ++pi) {
    __syncthreads();
    if ((w >> 1) == pi) {
#pragma unroll
      for (int qh = 0; qh < 2; ++qh)
#pragma unroll
        for (int ci = 0; ci < 2; ++ci)
#pragma unroll
          for (int r = 0; r < 16; ++r) {
            const int qcol = (w & 1) * 64 + qh * 32 + 8 * (r >> 2) + 4 * lh + (r & 3);
            Otb[(ci * 32 + l31) * 132 + qcol] = f32_to_bf16(accO[qh][ci][r]);
          }
    }
    __syncthreads();
    {
      const int ch = t >> 2, part = t & 3;
      const unsigned short* src = Otb + ch * 132 + part * 32;
      unsigned short* dst = Opart + (((size_t)ks * 4 + nb) * 64 + ch) * HW +
                            qb + pi * 128 + part * 32;
#pragma unroll
      for (int i = 0; i < 4; ++i) {
        V8 v;
        v.h[0] = *(const us4*)(src + i * 8);
        v.h[1] = *(const us4*)(src + i * 8 + 4);
        *(us8*)(dst + i * 8) = v.s;
      }
    }
  }
}

// ---------------------------------------------------------------------------
// Combine: out[n][c][p] = sum_ks O[ks][n][c][p] / sum_ks l[ks][n][p].
// ---------------------------------------------------------------------------
__global__ __launch_bounds__(256) void combine_kernel(
    const unsigned short* __restrict__ Opart, const float* __restrict__ Lpart,
    float* __restrict__ out) {
  const int tid = blockIdx.x * 256 + threadIdx.x;
  const size_t e = (size_t)tid * 4;
  float4 o = {0.f, 0.f, 0.f, 0.f};
#pragma unroll
  for (int ks = 0; ks < KS; ++ks) {
    const us4 v = *(const us4*)(Opart + (size_t)ks * (4 * 64 * HW) + e);
    o.x += bf16_bits_to_f32(v[0]);
    o.y += bf16_bits_to_f32(v[1]);
    o.z += bf16_bits_to_f32(v[2]);
    o.w += bf16_bits_to_f32(v[3]);
  }
  const int n = (int)(e / (64 * HW));
  const int p = (int)(e % HW);
  float4 l = {0.f, 0.f, 0.f, 0.f};
#pragma unroll
  for (int ks = 0; ks < KS; ++ks) {
    const float4 v = *(const float4*)(Lpart + ((size_t)ks * 4 + n) * HW + p);
    l.x += v.x; l.y += v.y; l.z += v.z; l.w += v.w;
  }
  float4 r;
  r.x = o.x / l.x; r.y = o.y / l.y; r.z = o.z / l.z; r.w = o.w / l.w;
  *(float4*)(out + e) = r;
}

extern "C" void kernel_launch(void* const* d_in, const int* in_sizes, int n_in,
                              void* d_out, int out_size, void* d_ws, size_t ws_size,
                              hipStream_t stream) {
  const float* x = (const float*)d_in[0];
  const float* w1 = (const float*)d_in[1];
  const float* b1 = (const float*)d_in[2];
  const float* w2 = (const float*)d_in[3];
  const float* b2 = (const float*)d_in[4];
  const float* w3 = (const float*)d_in[5];
  const float* b3 = (const float*)d_in[6];
  float* out = (float*)d_out;

  // ws: Q,K,V bf16 (9.8 MB) + Opart bf16 KS=10 (32.8 MB) + Lpart (1.0 MB)
  unsigned short* Q = (unsigned short*)d_ws;
  unsigned short* K = Q + (size_t)4 * HW * 64;
  unsigned short* V = K + (size_t)4 * HW * 64;
  unsigned short* Opart = V + (size_t)4 * HW * 64;
  float* Lpart = (float*)(Opart + (size_t)KS * 4 * 64 * HW);

  conv_kernel<<<dim3(50, 4), 256, 0, stream>>>(x, w1, b1, w2, b2, w3, b3,
                                               Q, K, V);
  attn_kernel<<<1000, 256, 0, stream>>>(Q, K, V, Opart, Lpart);
  combine_kernel<<<1600, 256, 0, stream>>>(Opart, Lpart, out);
}